// Round 13
// baseline (379.963 us; speedup 1.0000x reference)
//
#include <hip/hip_runtime.h>

#define B_ 64
#define T_ 243
#define J_ 17
#define C_ 128
#define JC (J_*C_)            // 2176
#define NTOT (B_*T_*J_*C_)    // 33841152
#define NBLK 1088

// LDS layout (bytes). fp8 rows padded to 136 B (bank de-alias).
//   [0,     34816)  ylds : fp8 [256][136]
//   [34816, 69632)  yv   : fp8 [256][136]  (0.25*(y@Vw^T+Vb))
//   [69632, 70656)  nbr  : u32 [256]  (4 x u8 idx)
//   [70656, 71680)  bnw_s: f32 [256] (pre-scaled)
//   [71680, 72704)  bnb_s: f32 [256]
//   [72704, 73216)  ub_s : f32 [128]
//   [73216, 73728)  ls_s : f32 [128]
#define YOFF    0
#define YVOFF   34816
#define NBROFF  69632
#define BNWOFF  70656
#define BNBOFF  71680
#define UBOFF   72704
#define LSOFF   73216
#define SMEM_BYTES 73728
#define YSTR 136

typedef float f32x4 __attribute__((ext_vector_type(4)));
typedef float f32x2 __attribute__((ext_vector_type(2)));

__device__ __forceinline__ unsigned pkf8(float a, float b, float c, float d){
  int p = __builtin_amdgcn_cvt_pk_fp8_f32(a, b, 0, false);
  p = __builtin_amdgcn_cvt_pk_fp8_f32(c, d, p, true);
  return (unsigned)p;
}

template<int CTRL>
__device__ __forceinline__ float dppadd(float v){
  int t = __builtin_amdgcn_update_dpp(0, __float_as_int(v), CTRL, 0xf, 0xf, true);
  return v + __int_as_float(t);
}
__device__ __forceinline__ float swz16(float v){
  return __int_as_float(__builtin_amdgcn_ds_swizzle(__float_as_int(v), 0x401F));
}

#define PINS(x, a0,a1,a2,a3) do { \
  float t_ = fmaxf(a0,(x)), m_ = fminf(a0,(x)); a0 = t_; \
  float t2_ = fmaxf(a1,m_); m_ = fminf(a1,m_); a1 = t2_; \
  float t3_ = fmaxf(a2,m_); m_ = fminf(a2,m_); a2 = t3_; \
  a3 = fmaxf(a3,m_); \
} while(0)
#define MM(p,q) do { float h_=fmaxf(p,q); q=fminf(p,q); p=h_; } while(0)

extern "C" __global__ void __launch_bounds__(1024, 8)
graphblock_kernel(const float* __restrict__ x, const float* __restrict__ att,
                  const float* __restrict__ lnw, const float* __restrict__ lnb,
                  const float* __restrict__ Uw, const float* __restrict__ Ubv,
                  const float* __restrict__ Vw, const float* __restrict__ Vbv,
                  const float* __restrict__ bnw, const float* __restrict__ bnb,
                  const float* __restrict__ ls1, float* __restrict__ out)
{
  extern __shared__ char smem[];
  const int tid = threadIdx.x;
  const int w = tid >> 6, l = tid & 63;
  const int lr = l & 15, lg = l >> 4;
  const int cs = w & 7, rh = w >> 3;
  const int ch0 = cs*16 + lg*4;

  // ---- tables staged once (n-independent) ----
  if (tid < 256) {
    bool v = tid < T_;
    ((float*)(smem+BNWOFF))[tid] = v ? bnw[tid]*rsqrtf(1.0f+1e-5f) : 0.f;
    ((float*)(smem+BNBOFF))[tid] = v ? bnb[tid] : 0.f;
  } else if (tid < 384) {
    int c = tid - 256;
    ((float*)(smem+UBOFF))[c] = Ubv[c];
    ((float*)(smem+LSOFF))[c] = ls1[c];
  }

  const int k = blockIdx.x;
  const int niter = (k < (NBLK - 1024)) ? 2 : 1;   // blocks 0..63 do n and n+1024

  for (int it = 0; it < niter; ++it) {
    const int n = k + it*1024;
    const int b = n / J_, j = n % J_;
    const long nbase = (long)b*T_*JC + (long)j*C_;

    // ---- Phase A: LayerNorm -> ylds fp8 ; 2 batches of 4-deep prefetch ----
    {
      const int lh = l >> 5, lc = l & 31;
      const float4 lw4 = *(const float4*)(lnw + lc*4);
      const float4 lb4 = *(const float4*)(lnb + lc*4);
      #pragma unroll
      for (int half=0; half<2; half++){
        float4 p[4];
        #pragma unroll
        for (int q2=0;q2<4;q2++){
          const int r = (half*4+q2)*32 + w*2 + lh;
          p[q2] = make_float4(0.f,0.f,0.f,0.f);
          if (r < T_) p[q2] = *(const float4*)(x + nbase + (long)r*JC + lc*4);
        }
        #pragma unroll
        for (int q2=0;q2<4;q2++){
          const int r = (half*4+q2)*32 + w*2 + lh;
          unsigned pk = 0u;
          if (r < T_) {
            float4 v = p[q2];
            float s = (v.x+v.y)+(v.z+v.w);
            float q = (v.x*v.x+v.y*v.y)+(v.z*v.z+v.w*v.w);
            s = dppadd<0xB1>(s);  q = dppadd<0xB1>(q);
            s = dppadd<0x4E>(s);  q = dppadd<0x4E>(q);
            s = dppadd<0x124>(s); q = dppadd<0x124>(q);
            s = dppadd<0x128>(s); q = dppadd<0x128>(q);
            s += swz16(s);        q += swz16(q);
            float mu = s*(1.f/128.f);
            float rs = rsqrtf(q*(1.f/128.f)-mu*mu+1e-5f);
            pk = pkf8((v.x-mu)*rs*lw4.x+lb4.x, (v.y-mu)*rs*lw4.y+lb4.y,
                      (v.z-mu)*rs*lw4.z+lb4.z, (v.w-mu)*rs*lw4.w+lb4.w);
          }
          *(unsigned*)(smem + YOFF + r*YSTR + lc*4) = pk;
        }
      }
    }
    __syncthreads();   // barrier 1: ylds + tables ready

    // ---- Phase C: sim (fp8 MFMA, swapped operands) + per-lane top-4 ----
    {
      const int tcol = w*16 + lr;
      long bfr[4];
      #pragma unroll
      for (int kk=0;kk<4;kk++)
        bfr[kk] = *(const long*)(smem + YOFF + tcol*YSTR + kk*32 + lg*8);
      float v0=-3e38f, v1=-3e38f, v2=-3e38f, v3=-3e38f;
      #pragma unroll 4
      for (int st=0; st<16; st++){
        f32x4 acc = {0.f,0.f,0.f,0.f};
        #pragma unroll
        for (int kk=0;kk<4;kk++){
          long afr = *(const long*)(smem + YOFF + (st*16+lr)*YSTR + kk*32 + lg*8);
          acc = __builtin_amdgcn_mfma_f32_16x16x32_fp8_fp8(afr, bfr[kk], acc, 0,0,0);
        }
        #pragma unroll
        for (int reg=0;reg<4;reg++){
          const int sidx = st*16 + lg*4 + reg;
          unsigned uu = (__float_as_uint(acc[reg]) & 0xffffff00u) | (unsigned)(sidx & 0xff);
          float pv = (sidx < T_) ? __uint_as_float(uu) : -3e38f;
          PINS(pv, v0,v1,v2,v3);
        }
      }
      #pragma unroll
      for (int m=16;m<64;m<<=1){
        float c0=__shfl_xor(v0,m,64), c1=__shfl_xor(v1,m,64),
              c2=__shfl_xor(v2,m,64), c3=__shfl_xor(v3,m,64);
        float d0=fmaxf(v0,c3), d1=fmaxf(v1,c2), d2=fmaxf(v2,c1), d3=fmaxf(v3,c0);
        MM(d0,d1); MM(d2,d3); MM(d0,d2); MM(d1,d3); MM(d1,d2);
        v0=d0; v1=d1; v2=d2; v3=d3;
      }
      if (lg==0){
        unsigned pk = (__float_as_uint(v0) & 0xffu)
                    | ((__float_as_uint(v1) & 0xffu) << 8)
                    | ((__float_as_uint(v2) & 0xffu) << 16)
                    | ((__float_as_uint(v3) & 0xffu) << 24);
        *(unsigned*)(smem + NBROFF + tcol*4) = pk;
      }
    }

    // ---- load + quantize weights to fp8 frags ----
    long ufr[4], vfr[4];
    {
      const int crw = cs*16 + lr;
      #pragma unroll
      for (int kk=0;kk<4;kk++){
        const float4* pu = (const float4*)(Uw + crw*C_ + kk*32 + lg*8);
        float4 a = pu[0], c = pu[1];
        union { long v; unsigned u[2]; } r;
        r.u[0] = pkf8(a.x,a.y,a.z,a.w); r.u[1] = pkf8(c.x,c.y,c.z,c.w);
        ufr[kk] = r.v;
        const float4* pv = (const float4*)(Vw + crw*C_ + kk*32 + lg*8);
        a = pv[0]; c = pv[1];
        r.u[0] = pkf8(a.x,a.y,a.z,a.w); r.u[1] = pkf8(c.x,c.y,c.z,c.w);
        vfr[kk] = r.v;
      }
    }
    const float4 vb4 = *(const float4*)(Vbv + ch0);

    // first pass-2 tile x/att prefetch: issue BEFORE pass 1 (hides under yV MFMA)
    int   t_n  = (rh*8)*16 + lr;
    bool  ok_n = t_n < T_;
    long  g_n  = nbase + (long)t_n*JC + ch0;
    float4 px = make_float4(0,0,0,0), pa = make_float4(0,0,0,0);
    if (ok_n){ px = *(const float4*)(x+g_n); pa = *(const float4*)(att+g_n); }

    // ---- Pass 1: yv = 0.25*(y@Vw^T + Vb) -> fp8 LDS ----
    #pragma unroll
    for (int tt=0; tt<8; tt++){
      const int t = (rh*8+tt)*16 + lr;
      f32x4 accV = {0.f,0.f,0.f,0.f};
      #pragma unroll
      for (int kk=0;kk<4;kk++){
        long yf = *(const long*)(smem + YOFF + t*YSTR + kk*32 + lg*8);
        accV = __builtin_amdgcn_mfma_f32_16x16x32_fp8_fp8(vfr[kk], yf, accV, 0,0,0);
      }
      *(unsigned*)(smem + YVOFF + t*YSTR + ch0) =
          pkf8(0.25f*(accV[0]+vb4.x), 0.25f*(accV[1]+vb4.y),
               0.25f*(accV[2]+vb4.z), 0.25f*(accV[3]+vb4.w));
    }
    __syncthreads();   // barrier 2: nbr + yv ready

    // ---- Pass 2: yU MFMA + gather + BN + ReLU + epilogue ----
    const float4 ub4 = *(const float4*)((const float*)(smem+UBOFF) + ch0);
    const float4 ls4 = *(const float4*)((const float*)(smem+LSOFF) + ch0);

    #pragma unroll
    for (int tt=0; tt<8; tt++){
      const int   t  = t_n;
      const bool  ok = ok_n;
      const long  g  = g_n;
      const float4 x4 = px, a4 = pa;
      if (tt < 7){
        t_n  = (rh*8+tt+1)*16 + lr;
        ok_n = t_n < T_;
        g_n  = nbase + (long)t_n*JC + ch0;
        px = make_float4(0,0,0,0); pa = make_float4(0,0,0,0);
        if (ok_n){ px = *(const float4*)(x+g_n); pa = *(const float4*)(att+g_n); }
      }
      f32x4 accU = {0.f,0.f,0.f,0.f};
      #pragma unroll
      for (int kk=0;kk<4;kk++){
        long yf = *(const long*)(smem + YOFF + t*YSTR + kk*32 + lg*8);
        accU = __builtin_amdgcn_mfma_f32_16x16x32_fp8_fp8(ufr[kk], yf, accU, 0,0,0);
      }
      unsigned nb = *(const unsigned*)(smem + NBROFF + t*4);
      const int s0 = (int)(nb & 0xffu), s1 = (int)((nb>>8)&0xffu),
                s2 = (int)((nb>>16)&0xffu), s3 = (int)((nb>>24)&0xffu);
      float ag0=0,ag1=0,ag2=0,ag3=0;
      {
        unsigned q; f32x2 e, o2;
        q = *(const unsigned*)(smem+YVOFF + s0*YSTR + ch0);
        e = __builtin_amdgcn_cvt_pk_f32_fp8(q,false); o2 = __builtin_amdgcn_cvt_pk_f32_fp8(q,true);
        ag0+=e[0]; ag1+=e[1]; ag2+=o2[0]; ag3+=o2[1];
        q = *(const unsigned*)(smem+YVOFF + s1*YSTR + ch0);
        e = __builtin_amdgcn_cvt_pk_f32_fp8(q,false); o2 = __builtin_amdgcn_cvt_pk_f32_fp8(q,true);
        ag0+=e[0]; ag1+=e[1]; ag2+=o2[0]; ag3+=o2[1];
        q = *(const unsigned*)(smem+YVOFF + s2*YSTR + ch0);
        e = __builtin_amdgcn_cvt_pk_f32_fp8(q,false); o2 = __builtin_amdgcn_cvt_pk_f32_fp8(q,true);
        ag0+=e[0]; ag1+=e[1]; ag2+=o2[0]; ag3+=o2[1];
        q = *(const unsigned*)(smem+YVOFF + s3*YSTR + ch0);
        e = __builtin_amdgcn_cvt_pk_f32_fp8(q,false); o2 = __builtin_amdgcn_cvt_pk_f32_fp8(q,true);
        ag0+=e[0]; ag1+=e[1]; ag2+=o2[0]; ag3+=o2[1];
      }
      float yo0,yo1,yo2,yo3;
      {
        unsigned q = *(const unsigned*)(smem + YOFF + t*YSTR + ch0);
        f32x2 e = __builtin_amdgcn_cvt_pk_f32_fp8(q,false);
        f32x2 o2 = __builtin_amdgcn_cvt_pk_f32_fp8(q,true);
        yo0=e[0]; yo1=e[1]; yo2=o2[0]; yo3=o2[1];
      }
      const float bw = ((const float*)(smem+BNWOFF))[t];
      const float bb = ((const float*)(smem+BNBOFF))[t];
      f32x4 o, gf;
      {
        float h = (accU[0] + ag0 + ub4.x)*bw + bb;
        float gx = ls4.x * fmaxf(0.f, yo0 + h);
        o[0] = gx + a4.x + x4.x; gf[0] = gx*0.5f;
      }{
        float h = (accU[1] + ag1 + ub4.y)*bw + bb;
        float gx = ls4.y * fmaxf(0.f, yo1 + h);
        o[1] = gx + a4.y + x4.y; gf[1] = gx*0.5f;
      }{
        float h = (accU[2] + ag2 + ub4.z)*bw + bb;
        float gx = ls4.z * fmaxf(0.f, yo2 + h);
        o[2] = gx + a4.z + x4.z; gf[2] = gx*0.5f;
      }{
        float h = (accU[3] + ag3 + ub4.w)*bw + bb;
        float gx = ls4.w * fmaxf(0.f, yo3 + h);
        o[3] = gx + a4.w + x4.w; gf[3] = gx*0.5f;
      }
      if (ok){
        *(f32x4*)(out+g)      = o;
        *(f32x4*)(out+NTOT+g) = gf;
      }
    }

    if (it+1 < niter) __syncthreads();   // protect LDS reuse across n iterations
  }
}

extern "C" void kernel_launch(void* const* d_in, const int* in_sizes, int n_in,
                              void* d_out, int out_size, void* d_ws, size_t ws_size,
                              hipStream_t stream) {
  hipFuncSetAttribute(reinterpret_cast<const void*>(graphblock_kernel),
                      hipFuncAttributeMaxDynamicSharedMemorySize, SMEM_BYTES);
  dim3 grid(1024);
  dim3 block(1024);
  graphblock_kernel<<<grid, block, SMEM_BYTES, stream>>>(
      (const float*)d_in[0],  // x
      (const float*)d_in[1],  // attention_feat
      (const float*)d_in[2],  // ln_w
      (const float*)d_in[3],  // ln_b
      (const float*)d_in[4],  // Uw
      (const float*)d_in[5],  // Ub
      (const float*)d_in[6],  // Vw
      (const float*)d_in[7],  // Vb
      (const float*)d_in[8],  // bn_w
      (const float*)d_in[9],  // bn_b
      (const float*)d_in[10], // ls1
      (float*)d_out);
}

// Round 14
// 303.670 us; speedup vs baseline: 1.2512x; 1.2512x over previous
//
#include <hip/hip_runtime.h>

#define B_ 64
#define T_ 243
#define J_ 17
#define C_ 128
#define JC (J_*C_)            // 2176
#define NTOT (B_*T_*J_*C_)    // 33841152

// LDS layout (bytes). fp8 rows padded to 136 B (bank de-alias).
//   [0,     34816)  ylds : fp8 [256][136]
//   [34816, 35840)  nbr  : u32 [256]  (4 x u8 idx)
//   [35840, 36864)  bnw_s: f32 [256] (pre-scaled)
//   [36864, 37888)  bnb_s: f32 [256]
//   [37888, 38400)  bias : f32 [128]  (Ub + Vb)
//   [38400, 38912)  ls_s : f32 [128]
#define YOFF    0
#define NBROFF  34816
#define BNWOFF  35840
#define BNBOFF  36864
#define BIASOFF 37888
#define LSOFF   38400
#define SMEM_BYTES 38912
#define YSTR 136

typedef float f32x4 __attribute__((ext_vector_type(4)));
typedef float f32x2 __attribute__((ext_vector_type(2)));

__device__ __forceinline__ unsigned pkf8(float a, float b, float c, float d){
  int p = __builtin_amdgcn_cvt_pk_fp8_f32(a, b, 0, false);
  p = __builtin_amdgcn_cvt_pk_fp8_f32(c, d, p, true);
  return (unsigned)p;
}

template<int CTRL>
__device__ __forceinline__ float dppadd(float v){
  int t = __builtin_amdgcn_update_dpp(0, __float_as_int(v), CTRL, 0xf, 0xf, true);
  return v + __int_as_float(t);
}
__device__ __forceinline__ float swz16(float v){
  return __int_as_float(__builtin_amdgcn_ds_swizzle(__float_as_int(v), 0x401F));
}

#define PINS(x, a0,a1,a2,a3) do { \
  float t_ = fmaxf(a0,(x)), m_ = fminf(a0,(x)); a0 = t_; \
  float t2_ = fmaxf(a1,m_); m_ = fminf(a1,m_); a1 = t2_; \
  float t3_ = fmaxf(a2,m_); m_ = fminf(a2,m_); a2 = t3_; \
  a3 = fmaxf(a3,m_); \
} while(0)
#define MM(p,q) do { float h_=fmaxf(p,q); q=fminf(p,q); p=h_; } while(0)

extern "C" __global__ void __launch_bounds__(512, 8)
graphblock_kernel(const float* __restrict__ x, const float* __restrict__ att,
                  const float* __restrict__ lnw, const float* __restrict__ lnb,
                  const float* __restrict__ Uw, const float* __restrict__ Ubv,
                  const float* __restrict__ Vw, const float* __restrict__ Vbv,
                  const float* __restrict__ bnw, const float* __restrict__ bnb,
                  const float* __restrict__ ls1, float* __restrict__ out)
{
  extern __shared__ char smem[];
  const int tid = threadIdx.x;
  const int w = tid >> 6, l = tid & 63;    // 8 waves
  const int lr = l & 15, lg = l >> 4;
  const int n = blockIdx.x, b = n / J_, j = n % J_;
  const long nbase = (long)b*T_*JC + (long)j*C_;
  const int ch0 = w*16 + lg*4;             // lane's 4-channel base (UV pass)

  // ---- table staging ----
  if (tid < 256) {
    bool v = tid < T_;
    ((float*)(smem+BNWOFF))[tid] = v ? bnw[tid]*rsqrtf(1.0f+1e-5f) : 0.f;
    ((float*)(smem+BNBOFF))[tid] = v ? bnb[tid] : 0.f;
  } else if (tid < 384) {
    int c = tid - 256;
    ((float*)(smem+BIASOFF))[c] = Ubv[c] + Vbv[c];
    ((float*)(smem+LSOFF))[c]   = ls1[c];
  }

  // ---- Phase A: LayerNorm -> ylds fp8 (16 rows/wave over 2 groups of 8) ----
  {
    const int lh = l >> 5, lc = l & 31;
    const float4 lw4 = *(const float4*)(lnw + lc*4);
    const float4 lb4 = *(const float4*)(lnb + lc*4);
    #pragma unroll
    for (int g2=0; g2<2; g2++){
      float4 p[8];
      #pragma unroll
      for (int i=0;i<8;i++){
        const int r = (g2*8+i)*16 + w*2 + lh;
        p[i] = make_float4(0.f,0.f,0.f,0.f);
        if (r < T_) p[i] = *(const float4*)(x + nbase + (long)r*JC + lc*4);
      }
      #pragma unroll
      for (int i=0;i<8;i++){
        const int r = (g2*8+i)*16 + w*2 + lh;
        unsigned pk = 0u;
        if (r < T_) {
          float4 v = p[i];
          float s = (v.x+v.y)+(v.z+v.w);
          float q = (v.x*v.x+v.y*v.y)+(v.z*v.z+v.w*v.w);
          s = dppadd<0xB1>(s);  q = dppadd<0xB1>(q);
          s = dppadd<0x4E>(s);  q = dppadd<0x4E>(q);
          s = dppadd<0x124>(s); q = dppadd<0x124>(q);
          s = dppadd<0x128>(s); q = dppadd<0x128>(q);
          s += swz16(s);        q += swz16(q);
          float mu = s*(1.f/128.f);
          float rs = rsqrtf(q*(1.f/128.f)-mu*mu+1e-5f);
          pk = pkf8((v.x-mu)*rs*lw4.x+lb4.x, (v.y-mu)*rs*lw4.y+lb4.y,
                    (v.z-mu)*rs*lw4.z+lb4.z, (v.w-mu)*rs*lw4.w+lb4.w);
        }
        *(unsigned*)(smem + YOFF + r*YSTR + lc*4) = pk;
      }
    }
  }
  __syncthreads();   // barrier 1: ylds + tables ready

  // ---- Phase C: sim (fp8 MFMA, swapped operands) + per-lane top-4; 2 halves ----
  #pragma unroll
  for (int half=0; half<2; half++){
    const int tcol = half*128 + w*16 + lr;   // this lane's t (D column)
    long bfr[4];
    #pragma unroll
    for (int kk=0;kk<4;kk++)
      bfr[kk] = *(const long*)(smem + YOFF + tcol*YSTR + kk*32 + lg*8);
    float v0=-3e38f, v1=-3e38f, v2=-3e38f, v3=-3e38f;
    #pragma unroll 4
    for (int st=0; st<16; st++){
      f32x4 acc = {0.f,0.f,0.f,0.f};
      #pragma unroll
      for (int kk=0;kk<4;kk++){
        long afr = *(const long*)(smem + YOFF + (st*16+lr)*YSTR + kk*32 + lg*8);
        acc = __builtin_amdgcn_mfma_f32_16x16x32_fp8_fp8(afr, bfr[kk], acc, 0,0,0);
      }
      #pragma unroll
      for (int reg=0;reg<4;reg++){
        const int sidx = st*16 + lg*4 + reg;
        unsigned uu = (__float_as_uint(acc[reg]) & 0xffffff00u) | (unsigned)(sidx & 0xff);
        float pv = (sidx < T_) ? __uint_as_float(uu) : -3e38f;
        PINS(pv, v0,v1,v2,v3);
      }
    }
    #pragma unroll
    for (int m=16;m<64;m<<=1){
      float c0=__shfl_xor(v0,m,64), c1=__shfl_xor(v1,m,64),
            c2=__shfl_xor(v2,m,64), c3=__shfl_xor(v3,m,64);
      float d0=fmaxf(v0,c3), d1=fmaxf(v1,c2), d2=fmaxf(v2,c1), d3=fmaxf(v3,c0);
      MM(d0,d1); MM(d2,d3); MM(d0,d2); MM(d1,d3); MM(d1,d2);
      v0=d0; v1=d1; v2=d2; v3=d3;
    }
    if (lg==0){
      unsigned pk = (__float_as_uint(v0) & 0xffu)
                  | ((__float_as_uint(v1) & 0xffu) << 8)
                  | ((__float_as_uint(v2) & 0xffu) << 16)
                  | ((__float_as_uint(v3) & 0xffu) << 24);
      *(unsigned*)(smem + NBROFF + tcol*4) = pk;
    }
  }

  // ---- load + quantize weights to fp8 frags; V pre-scaled by 0.25 ----
  long ufr[4], vfr[4];
  {
    const int crw = w*16 + lr;
    #pragma unroll
    for (int kk=0;kk<4;kk++){
      const float4* pu = (const float4*)(Uw + crw*C_ + kk*32 + lg*8);
      float4 a = pu[0], c = pu[1];
      union { long v; unsigned u[2]; } r;
      r.u[0] = pkf8(a.x,a.y,a.z,a.w); r.u[1] = pkf8(c.x,c.y,c.z,c.w);
      ufr[kk] = r.v;
      const float4* pv = (const float4*)(Vw + crw*C_ + kk*32 + lg*8);
      a = pv[0]; c = pv[1];
      r.u[0] = pkf8(0.25f*a.x,0.25f*a.y,0.25f*a.z,0.25f*a.w);
      r.u[1] = pkf8(0.25f*c.x,0.25f*c.y,0.25f*c.z,0.25f*c.w);
      vfr[kk] = r.v;
    }
  }
  __syncthreads();   // barrier 2: nbr ready (y unchanged)

  // ---- UV pass: accU = y@Uw^T ; accV = sum_i mfma(0.25*V, y[nbr_i]) ; epilogue ----
  int   t_n  = lr;
  bool  ok_n = true;
  long  g_n  = nbase + (long)t_n*JC + ch0;
  float4 px = *(const float4*)(x+g_n), pa = *(const float4*)(att+g_n);

  #pragma unroll
  for (int tile=0; tile<16; tile++){
    const int   t  = t_n;
    const bool  ok = ok_n;
    const long  g  = g_n;
    const float4 x4 = px, a4 = pa;
    if (tile < 15){
      t_n  = (tile+1)*16 + lr;
      ok_n = t_n < T_;
      g_n  = nbase + (long)t_n*JC + ch0;
      px = make_float4(0,0,0,0); pa = make_float4(0,0,0,0);
      if (ok_n){ px = *(const float4*)(x+g_n); pa = *(const float4*)(att+g_n); }
    }
    // neighbor indices for this lane's t (same for all lg -> LDS broadcast)
    const unsigned nb = *(const unsigned*)(smem + NBROFF + t*4);
    const int s0 = (int)(nb & 0xffu), s1 = (int)((nb>>8)&0xffu),
              s2 = (int)((nb>>16)&0xffu), s3 = (int)((nb>>24)&0xffu);
    f32x4 accU = {0.f,0.f,0.f,0.f}, accV = {0.f,0.f,0.f,0.f};
    #pragma unroll
    for (int kk=0;kk<4;kk++){
      const int co = kk*32 + lg*8;
      long yf = *(const long*)(smem + YOFF + t*YSTR + co);
      accU = __builtin_amdgcn_mfma_f32_16x16x32_fp8_fp8(ufr[kk], yf, accU, 0,0,0);
      long b0 = *(const long*)(smem + YOFF + s0*YSTR + co);
      accV = __builtin_amdgcn_mfma_f32_16x16x32_fp8_fp8(vfr[kk], b0, accV, 0,0,0);
      long b1 = *(const long*)(smem + YOFF + s1*YSTR + co);
      accV = __builtin_amdgcn_mfma_f32_16x16x32_fp8_fp8(vfr[kk], b1, accV, 0,0,0);
      long b2 = *(const long*)(smem + YOFF + s2*YSTR + co);
      accV = __builtin_amdgcn_mfma_f32_16x16x32_fp8_fp8(vfr[kk], b2, accV, 0,0,0);
      long b3 = *(const long*)(smem + YOFF + s3*YSTR + co);
      accV = __builtin_amdgcn_mfma_f32_16x16x32_fp8_fp8(vfr[kk], b3, accV, 0,0,0);
    }
    float yo0,yo1,yo2,yo3;
    {
      unsigned q = *(const unsigned*)(smem + YOFF + t*YSTR + ch0);
      f32x2 e = __builtin_amdgcn_cvt_pk_f32_fp8(q,false);
      f32x2 o2 = __builtin_amdgcn_cvt_pk_f32_fp8(q,true);
      yo0=e[0]; yo1=e[1]; yo2=o2[0]; yo3=o2[1];
    }
    const float  bw = ((const float*)(smem+BNWOFF))[t];
    const float  bb = ((const float*)(smem+BNBOFF))[t];
    const float4 uv4 = *(const float4*)((const float*)(smem+BIASOFF) + ch0);
    const float4 ls4 = *(const float4*)((const float*)(smem+LSOFF)   + ch0);
    f32x4 o, gf;
    {
      float h = (accU[0] + accV[0] + uv4.x)*bw + bb;
      float gx = ls4.x * fmaxf(0.f, yo0 + h);
      o[0] = gx + a4.x + x4.x; gf[0] = gx*0.5f;
    }{
      float h = (accU[1] + accV[1] + uv4.y)*bw + bb;
      float gx = ls4.y * fmaxf(0.f, yo1 + h);
      o[1] = gx + a4.y + x4.y; gf[1] = gx*0.5f;
    }{
      float h = (accU[2] + accV[2] + uv4.z)*bw + bb;
      float gx = ls4.z * fmaxf(0.f, yo2 + h);
      o[2] = gx + a4.z + x4.z; gf[2] = gx*0.5f;
    }{
      float h = (accU[3] + accV[3] + uv4.w)*bw + bb;
      float gx = ls4.w * fmaxf(0.f, yo3 + h);
      o[3] = gx + a4.w + x4.w; gf[3] = gx*0.5f;
    }
    if (ok){
      *(f32x4*)(out+g)      = o;
      *(f32x4*)(out+NTOT+g) = gf;
    }
  }
}

extern "C" void kernel_launch(void* const* d_in, const int* in_sizes, int n_in,
                              void* d_out, int out_size, void* d_ws, size_t ws_size,
                              hipStream_t stream) {
  hipFuncSetAttribute(reinterpret_cast<const void*>(graphblock_kernel),
                      hipFuncAttributeMaxDynamicSharedMemorySize, SMEM_BYTES);
  dim3 grid(B_ * J_);
  dim3 block(512);
  graphblock_kernel<<<grid, block, SMEM_BYTES, stream>>>(
      (const float*)d_in[0],  // x
      (const float*)d_in[1],  // attention_feat
      (const float*)d_in[2],  // ln_w
      (const float*)d_in[3],  // ln_b
      (const float*)d_in[4],  // Uw
      (const float*)d_in[5],  // Ub
      (const float*)d_in[6],  // Vw
      (const float*)d_in[7],  // Vb
      (const float*)d_in[8],  // bn_w
      (const float*)d_in[9],  // bn_b
      (const float*)d_in[10], // ls1
      (float*)d_out);
}

// Round 15
// 201.220 us; speedup vs baseline: 1.8883x; 1.5091x over previous
//
#include <hip/hip_runtime.h>

#define B_ 64
#define T_ 243
#define J_ 17
#define C_ 128
#define JC (J_*C_)            // 2176
#define NTOT (B_*T_*J_*C_)    // 33841152

// LDS layout (bytes). fp8 rows padded to 136 B (bank de-alias).
//   [0,     34816)  ylds : fp8 [256][136]
//   [34816, 69632)  yv   : fp8 [256][136]  (0.25*(y@Vw^T+Vb))
//   [69632, 70656)  nbr  : u32 [256]  (4 x u8 idx)
//   [70656, 71680)  bnw_s: f32 [256] (pre-scaled)
//   [71680, 72704)  bnb_s: f32 [256]
//   [72704, 73216)  ub_s : f32 [128]
//   [73216, 73728)  ls_s : f32 [128]
#define YOFF    0
#define YVOFF   34816
#define NBROFF  69632
#define BNWOFF  70656
#define BNBOFF  71680
#define UBOFF   72704
#define LSOFF   73216
#define SMEM_BYTES 73728
#define YSTR 136

typedef float f32x4 __attribute__((ext_vector_type(4)));
typedef float f32x2 __attribute__((ext_vector_type(2)));

__device__ __forceinline__ unsigned pkf8(float a, float b, float c, float d){
  int p = __builtin_amdgcn_cvt_pk_fp8_f32(a, b, 0, false);
  p = __builtin_amdgcn_cvt_pk_fp8_f32(c, d, p, true);
  return (unsigned)p;
}

template<int CTRL>
__device__ __forceinline__ float dppadd(float v){
  int t = __builtin_amdgcn_update_dpp(0, __float_as_int(v), CTRL, 0xf, 0xf, true);
  return v + __int_as_float(t);
}
__device__ __forceinline__ float swz16(float v){
  return __int_as_float(__builtin_amdgcn_ds_swizzle(__float_as_int(v), 0x401F));
}

#define PINS(x, a0,a1,a2,a3) do { \
  float t_ = fmaxf(a0,(x)), m_ = fminf(a0,(x)); a0 = t_; \
  float t2_ = fmaxf(a1,m_); m_ = fminf(a1,m_); a1 = t2_; \
  float t3_ = fmaxf(a2,m_); m_ = fminf(a2,m_); a2 = t3_; \
  a3 = fmaxf(a3,m_); \
} while(0)
#define MM(p,q) do { float h_=fmaxf(p,q); q=fminf(p,q); p=h_; } while(0)

extern "C" __global__ void __launch_bounds__(1024, 8)
graphblock_kernel(const float* __restrict__ x, const float* __restrict__ att,
                  const float* __restrict__ lnw, const float* __restrict__ lnb,
                  const float* __restrict__ Uw, const float* __restrict__ Ubv,
                  const float* __restrict__ Vw, const float* __restrict__ Vbv,
                  const float* __restrict__ bnw, const float* __restrict__ bnb,
                  const float* __restrict__ ls1, float* __restrict__ out)
{
  extern __shared__ char smem[];
  const int tid = threadIdx.x;
  const int w = tid >> 6, l = tid & 63;
  const int lr = l & 15, lg = l >> 4;
  const int n = blockIdx.x, b = n / J_, j = n % J_;
  const long nbase = (long)b*T_*JC + (long)j*C_;
  const int cs = w & 7, rh = w >> 3;
  const int ch0 = cs*16 + lg*4;        // lane's 4-channel base in UV pass

  // ---- table staging ----
  if (tid < 256) {
    bool v = tid < T_;
    ((float*)(smem+BNWOFF))[tid] = v ? bnw[tid]*rsqrtf(1.0f+1e-5f) : 0.f;
    ((float*)(smem+BNBOFF))[tid] = v ? bnb[tid] : 0.f;
  } else if (tid < 384) {
    int c = tid - 256;
    ((float*)(smem+UBOFF))[c] = Ubv[c];
    ((float*)(smem+LSOFF))[c] = ls1[c];
  }

  // ---- Phase A: LayerNorm -> ylds fp8 ; DPP reductions ----
  {
    const int lh = l >> 5, lc = l & 31;
    const float4 lw4 = *(const float4*)(lnw + lc*4);
    const float4 lb4 = *(const float4*)(lnb + lc*4);
    float4 p[8];
    #pragma unroll
    for (int i=0;i<8;i++){
      const int r = i*32 + w*2 + lh;
      p[i] = make_float4(0.f,0.f,0.f,0.f);
      if (r < T_) p[i] = *(const float4*)(x + nbase + (long)r*JC + lc*4);
    }
    #pragma unroll
    for (int i=0;i<8;i++){
      const int r = i*32 + w*2 + lh;
      unsigned pk = 0u;
      if (r < T_) {
        float4 v = p[i];
        float s = (v.x+v.y)+(v.z+v.w);
        float q = (v.x*v.x+v.y*v.y)+(v.z*v.z+v.w*v.w);
        s = dppadd<0xB1>(s);  q = dppadd<0xB1>(q);
        s = dppadd<0x4E>(s);  q = dppadd<0x4E>(q);
        s = dppadd<0x124>(s); q = dppadd<0x124>(q);
        s = dppadd<0x128>(s); q = dppadd<0x128>(q);
        s += swz16(s);        q += swz16(q);
        float mu = s*(1.f/128.f);
        float rs = rsqrtf(q*(1.f/128.f)-mu*mu+1e-5f);
        pk = pkf8((v.x-mu)*rs*lw4.x+lb4.x, (v.y-mu)*rs*lw4.y+lb4.y,
                  (v.z-mu)*rs*lw4.z+lb4.z, (v.w-mu)*rs*lw4.w+lb4.w);
      }
      *(unsigned*)(smem + YOFF + r*YSTR + lc*4) = pk;
    }
  }
  __syncthreads();   // barrier 1: ylds + tables ready

  // ---- Phase C: sim (fp8 MFMA, swapped operands) + per-lane top-4 ----
  {
    const int tcol = w*16 + lr;         // this lane's t (D column)
    long bfr[4];
    #pragma unroll
    for (int kk=0;kk<4;kk++)
      bfr[kk] = *(const long*)(smem + YOFF + tcol*YSTR + kk*32 + lg*8);
    float v0=-3e38f, v1=-3e38f, v2=-3e38f, v3=-3e38f;
    #pragma unroll 4
    for (int st=0; st<16; st++){
      f32x4 acc = {0.f,0.f,0.f,0.f};
      #pragma unroll
      for (int kk=0;kk<4;kk++){
        long afr = *(const long*)(smem + YOFF + (st*16+lr)*YSTR + kk*32 + lg*8);
        acc = __builtin_amdgcn_mfma_f32_16x16x32_fp8_fp8(afr, bfr[kk], acc, 0,0,0);
      }
      #pragma unroll
      for (int reg=0;reg<4;reg++){
        const int sidx = st*16 + lg*4 + reg;
        unsigned uu = (__float_as_uint(acc[reg]) & 0xffffff00u) | (unsigned)(sidx & 0xff);
        float pv = (sidx < T_) ? __uint_as_float(uu) : -3e38f;
        PINS(pv, v0,v1,v2,v3);
      }
    }
    #pragma unroll
    for (int m=16;m<64;m<<=1){
      float c0=__shfl_xor(v0,m,64), c1=__shfl_xor(v1,m,64),
            c2=__shfl_xor(v2,m,64), c3=__shfl_xor(v3,m,64);
      float d0=fmaxf(v0,c3), d1=fmaxf(v1,c2), d2=fmaxf(v2,c1), d3=fmaxf(v3,c0);
      MM(d0,d1); MM(d2,d3); MM(d0,d2); MM(d1,d3); MM(d1,d2);
      v0=d0; v1=d1; v2=d2; v3=d3;
    }
    if (lg==0){
      unsigned pk = (__float_as_uint(v0) & 0xffu)
                  | ((__float_as_uint(v1) & 0xffu) << 8)
                  | ((__float_as_uint(v2) & 0xffu) << 16)
                  | ((__float_as_uint(v3) & 0xffu) << 24);
      *(unsigned*)(smem + NBROFF + tcol*4) = pk;
    }
  }

  // ---- load + quantize weights to fp8 frags (A-operand: row=out-channel) ----
  long ufr[4], vfr[4];
  {
    const int crw = cs*16 + lr;
    #pragma unroll
    for (int kk=0;kk<4;kk++){
      const float4* pu = (const float4*)(Uw + crw*C_ + kk*32 + lg*8);
      float4 a = pu[0], c = pu[1];
      union { long v; unsigned u[2]; } r;
      r.u[0] = pkf8(a.x,a.y,a.z,a.w); r.u[1] = pkf8(c.x,c.y,c.z,c.w);
      ufr[kk] = r.v;
      const float4* pv = (const float4*)(Vw + crw*C_ + kk*32 + lg*8);
      a = pv[0]; c = pv[1];
      r.u[0] = pkf8(a.x,a.y,a.z,a.w); r.u[1] = pkf8(c.x,c.y,c.z,c.w);
      vfr[kk] = r.v;
    }
  }
  const float4 vb4 = *(const float4*)(Vbv + ch0);

  // ---- Merged UV pass: per tile read A-frags ONCE -> accU (->fp8 regs) + yv (->LDS) ----
  unsigned hu[8];   // accU packed fp8x4 per tile
  unsigned yo[8];   // y (already fp8) dword at (t, ch0) per tile
  #pragma unroll
  for (int tt=0; tt<8; tt++){
    const int t = (rh*8+tt)*16 + lr;
    f32x4 accU = {0.f,0.f,0.f,0.f}, accV = {0.f,0.f,0.f,0.f};
    #pragma unroll
    for (int kk=0;kk<4;kk++){
      long yf = *(const long*)(smem + YOFF + t*YSTR + kk*32 + lg*8);
      accU = __builtin_amdgcn_mfma_f32_16x16x32_fp8_fp8(ufr[kk], yf, accU, 0,0,0);
      accV = __builtin_amdgcn_mfma_f32_16x16x32_fp8_fp8(vfr[kk], yf, accV, 0,0,0);
    }
    *(unsigned*)(smem + YVOFF + t*YSTR + ch0) =
        pkf8(0.25f*(accV[0]+vb4.x), 0.25f*(accV[1]+vb4.y),
             0.25f*(accV[2]+vb4.z), 0.25f*(accV[3]+vb4.w));
    hu[tt] = pkf8(accU[0], accU[1], accU[2], accU[3]);
    yo[tt] = *(const unsigned*)(smem + YOFF + t*YSTR + ch0);
  }
  __syncthreads();   // barrier 2: nbr + yv ready

  // ---- Pass 2 (no MFMA): gather + BN + ReLU + epilogue, x/att prefetch 1-ahead ----
  const float4 ub4 = *(const float4*)((const float*)(smem+UBOFF) + ch0);
  const float4 ls4 = *(const float4*)((const float*)(smem+LSOFF) + ch0);

  int   t_n  = (rh*8)*16 + lr;
  bool  ok_n = t_n < T_;
  long  g_n  = nbase + (long)t_n*JC + ch0;
  float4 px = make_float4(0,0,0,0), pa = make_float4(0,0,0,0);
  if (ok_n){ px = *(const float4*)(x+g_n); pa = *(const float4*)(att+g_n); }

  #pragma unroll
  for (int tt=0; tt<8; tt++){
    const int   t  = t_n;
    const bool  ok = ok_n;
    const long  g  = g_n;
    const float4 x4 = px, a4 = pa;
    if (tt < 7){
      t_n  = (rh*8+tt+1)*16 + lr;
      ok_n = t_n < T_;
      g_n  = nbase + (long)t_n*JC + ch0;
      px = make_float4(0,0,0,0); pa = make_float4(0,0,0,0);
      if (ok_n){ px = *(const float4*)(x+g_n); pa = *(const float4*)(att+g_n); }
    }
    unsigned nb = *(const unsigned*)(smem + NBROFF + t*4);
    const int s0 = (int)(nb & 0xffu), s1 = (int)((nb>>8)&0xffu),
              s2 = (int)((nb>>16)&0xffu), s3 = (int)((nb>>24)&0xffu);
    float ag0=0,ag1=0,ag2=0,ag3=0;
    {
      unsigned q; f32x2 e, o2;
      q = *(const unsigned*)(smem+YVOFF + s0*YSTR + ch0);
      e = __builtin_amdgcn_cvt_pk_f32_fp8(q,false); o2 = __builtin_amdgcn_cvt_pk_f32_fp8(q,true);
      ag0+=e[0]; ag1+=e[1]; ag2+=o2[0]; ag3+=o2[1];
      q = *(const unsigned*)(smem+YVOFF + s1*YSTR + ch0);
      e = __builtin_amdgcn_cvt_pk_f32_fp8(q,false); o2 = __builtin_amdgcn_cvt_pk_f32_fp8(q,true);
      ag0+=e[0]; ag1+=e[1]; ag2+=o2[0]; ag3+=o2[1];
      q = *(const unsigned*)(smem+YVOFF + s2*YSTR + ch0);
      e = __builtin_amdgcn_cvt_pk_f32_fp8(q,false); o2 = __builtin_amdgcn_cvt_pk_f32_fp8(q,true);
      ag0+=e[0]; ag1+=e[1]; ag2+=o2[0]; ag3+=o2[1];
      q = *(const unsigned*)(smem+YVOFF + s3*YSTR + ch0);
      e = __builtin_amdgcn_cvt_pk_f32_fp8(q,false); o2 = __builtin_amdgcn_cvt_pk_f32_fp8(q,true);
      ag0+=e[0]; ag1+=e[1]; ag2+=o2[0]; ag3+=o2[1];
    }
    float u0,u1,u2,u3, yo0,yo1,yo2,yo3;
    {
      f32x2 e = __builtin_amdgcn_cvt_pk_f32_fp8(hu[tt],false);
      f32x2 o2 = __builtin_amdgcn_cvt_pk_f32_fp8(hu[tt],true);
      u0=e[0]; u1=e[1]; u2=o2[0]; u3=o2[1];
      e = __builtin_amdgcn_cvt_pk_f32_fp8(yo[tt],false);
      o2 = __builtin_amdgcn_cvt_pk_f32_fp8(yo[tt],true);
      yo0=e[0]; yo1=e[1]; yo2=o2[0]; yo3=o2[1];
    }
    const float bw = ((const float*)(smem+BNWOFF))[t];
    const float bb = ((const float*)(smem+BNBOFF))[t];
    f32x4 o, gf;
    {
      float h = (u0 + ag0 + ub4.x)*bw + bb;
      float gx = ls4.x * fmaxf(0.f, yo0 + h);
      o[0] = gx + a4.x + x4.x; gf[0] = gx*0.5f;
    }{
      float h = (u1 + ag1 + ub4.y)*bw + bb;
      float gx = ls4.y * fmaxf(0.f, yo1 + h);
      o[1] = gx + a4.y + x4.y; gf[1] = gx*0.5f;
    }{
      float h = (u2 + ag2 + ub4.z)*bw + bb;
      float gx = ls4.z * fmaxf(0.f, yo2 + h);
      o[2] = gx + a4.z + x4.z; gf[2] = gx*0.5f;
    }{
      float h = (u3 + ag3 + ub4.w)*bw + bb;
      float gx = ls4.w * fmaxf(0.f, yo3 + h);
      o[3] = gx + a4.w + x4.w; gf[3] = gx*0.5f;
    }
    if (ok){
      *(f32x4*)(out+g)      = o;
      *(f32x4*)(out+NTOT+g) = gf;
    }
  }
}

extern "C" void kernel_launch(void* const* d_in, const int* in_sizes, int n_in,
                              void* d_out, int out_size, void* d_ws, size_t ws_size,
                              hipStream_t stream) {
  hipFuncSetAttribute(reinterpret_cast<const void*>(graphblock_kernel),
                      hipFuncAttributeMaxDynamicSharedMemorySize, SMEM_BYTES);
  dim3 grid(B_ * J_);
  dim3 block(1024);
  graphblock_kernel<<<grid, block, SMEM_BYTES, stream>>>(
      (const float*)d_in[0],  // x
      (const float*)d_in[1],  // attention_feat
      (const float*)d_in[2],  // ln_w
      (const float*)d_in[3],  // ln_b
      (const float*)d_in[4],  // Uw
      (const float*)d_in[5],  // Ub
      (const float*)d_in[6],  // Vw
      (const float*)d_in[7],  // Vb
      (const float*)d_in[8],  // bn_w
      (const float*)d_in[9],  // bn_b
      (const float*)d_in[10], // ls1
      (float*)d_out);
}

// Round 16
// 190.473 us; speedup vs baseline: 1.9948x; 1.0564x over previous
//
#include <hip/hip_runtime.h>

#define B_ 64
#define T_ 243
#define J_ 17
#define C_ 128
#define JC (J_*C_)            // 2176
#define NTOT (B_*T_*J_*C_)    // 33841152

// LDS layout (bytes). fp8 rows padded to 136 B (bank de-alias).
//   [0,     34816)  ylds : fp8 [256][136]
//   [34816, 69632)  yv   : fp8 [256][136]  (0.25*(y@Vw^T+Vb))
//   [69632, 70656)  nbr  : u32 [256]  (4 x u8 idx)
//   [70656, 71680)  bnw_s: f32 [256] (pre-scaled)
//   [71680, 72704)  bnb_s: f32 [256]
//   [72704, 73216)  ub_s : f32 [128]
//   [73216, 73728)  ls_s : f32 [128]
#define YOFF    0
#define YVOFF   34816
#define NBROFF  69632
#define BNWOFF  70656
#define BNBOFF  71680
#define UBOFF   72704
#define LSOFF   73216
#define SMEM_BYTES 73728
#define YSTR 136

typedef float f32x4 __attribute__((ext_vector_type(4)));
typedef float f32x2 __attribute__((ext_vector_type(2)));

__device__ __forceinline__ unsigned pkf8(float a, float b, float c, float d){
  int p = __builtin_amdgcn_cvt_pk_fp8_f32(a, b, 0, false);
  p = __builtin_amdgcn_cvt_pk_fp8_f32(c, d, p, true);
  return (unsigned)p;
}

template<int CTRL>
__device__ __forceinline__ float dppadd(float v){
  int t = __builtin_amdgcn_update_dpp(0, __float_as_int(v), CTRL, 0xf, 0xf, true);
  return v + __int_as_float(t);
}
__device__ __forceinline__ float swz16(float v){
  return __int_as_float(__builtin_amdgcn_ds_swizzle(__float_as_int(v), 0x401F));
}

#define PINS(x, a0,a1,a2,a3) do { \
  float t_ = fmaxf(a0,(x)), m_ = fminf(a0,(x)); a0 = t_; \
  float t2_ = fmaxf(a1,m_); m_ = fminf(a1,m_); a1 = t2_; \
  float t3_ = fmaxf(a2,m_); m_ = fminf(a2,m_); a2 = t3_; \
  a3 = fmaxf(a3,m_); \
} while(0)
#define MM(p,q) do { float h_=fmaxf(p,q); q=fminf(p,q); p=h_; } while(0)

extern "C" __global__ void __launch_bounds__(512, 4)
graphblock_kernel(const float* __restrict__ x, const float* __restrict__ att,
                  const float* __restrict__ lnw, const float* __restrict__ lnb,
                  const float* __restrict__ Uw, const float* __restrict__ Ubv,
                  const float* __restrict__ Vw, const float* __restrict__ Vbv,
                  const float* __restrict__ bnw, const float* __restrict__ bnb,
                  const float* __restrict__ ls1, float* __restrict__ out)
{
  extern __shared__ char smem[];
  const int tid = threadIdx.x;
  const int w = tid >> 6, l = tid & 63;    // 8 waves
  const int lr = l & 15, lg = l >> 4;
  const int n = blockIdx.x, b = n / J_, j = n % J_;
  const long nbase = (long)b*T_*JC + (long)j*C_;
  const int ch0 = w*16 + lg*4;             // lane's 4-channel base (UV passes)

  // ---- table staging ----
  if (tid < 256) {
    bool v = tid < T_;
    ((float*)(smem+BNWOFF))[tid] = v ? bnw[tid]*rsqrtf(1.0f+1e-5f) : 0.f;
    ((float*)(smem+BNBOFF))[tid] = v ? bnb[tid] : 0.f;
  } else if (tid < 384) {
    int c = tid - 256;
    ((float*)(smem+UBOFF))[c] = Ubv[c];
    ((float*)(smem+LSOFF))[c] = ls1[c];
  }

  // ---- Phase A: LayerNorm -> ylds fp8 ; 2 batches of 8-deep prefetch ----
  {
    const int lh = l >> 5, lc = l & 31;
    const float4 lw4 = *(const float4*)(lnw + lc*4);
    const float4 lb4 = *(const float4*)(lnb + lc*4);
    #pragma unroll
    for (int g2=0; g2<2; g2++){
      float4 p[8];
      #pragma unroll
      for (int i=0;i<8;i++){
        const int r = (g2*8+i)*16 + w*2 + lh;
        p[i] = make_float4(0.f,0.f,0.f,0.f);
        if (r < T_) p[i] = *(const float4*)(x + nbase + (long)r*JC + lc*4);
      }
      #pragma unroll
      for (int i=0;i<8;i++){
        const int r = (g2*8+i)*16 + w*2 + lh;
        unsigned pk = 0u;
        if (r < T_) {
          float4 v = p[i];
          float s = (v.x+v.y)+(v.z+v.w);
          float q = (v.x*v.x+v.y*v.y)+(v.z*v.z+v.w*v.w);
          s = dppadd<0xB1>(s);  q = dppadd<0xB1>(q);
          s = dppadd<0x4E>(s);  q = dppadd<0x4E>(q);
          s = dppadd<0x124>(s); q = dppadd<0x124>(q);
          s = dppadd<0x128>(s); q = dppadd<0x128>(q);
          s += swz16(s);        q += swz16(q);
          float mu = s*(1.f/128.f);
          float rs = rsqrtf(q*(1.f/128.f)-mu*mu+1e-5f);
          pk = pkf8((v.x-mu)*rs*lw4.x+lb4.x, (v.y-mu)*rs*lw4.y+lb4.y,
                    (v.z-mu)*rs*lw4.z+lb4.z, (v.w-mu)*rs*lw4.w+lb4.w);
        }
        *(unsigned*)(smem + YOFF + r*YSTR + lc*4) = pk;
      }
    }
  }
  __syncthreads();   // barrier 1: ylds + tables ready

  // ---- Phase C: sim (fp8 MFMA, swapped operands) + per-lane top-4; 2 halves ----
  #pragma unroll
  for (int half=0; half<2; half++){
    const int tcol = half*128 + w*16 + lr;   // this lane's t (D column)
    long bfr[4];
    #pragma unroll
    for (int kk=0;kk<4;kk++)
      bfr[kk] = *(const long*)(smem + YOFF + tcol*YSTR + kk*32 + lg*8);
    float v0=-3e38f, v1=-3e38f, v2=-3e38f, v3=-3e38f;
    #pragma unroll 4
    for (int st=0; st<16; st++){
      f32x4 acc = {0.f,0.f,0.f,0.f};
      #pragma unroll
      for (int kk=0;kk<4;kk++){
        long afr = *(const long*)(smem + YOFF + (st*16+lr)*YSTR + kk*32 + lg*8);
        acc = __builtin_amdgcn_mfma_f32_16x16x32_fp8_fp8(afr, bfr[kk], acc, 0,0,0);
      }
      #pragma unroll
      for (int reg=0;reg<4;reg++){
        const int sidx = st*16 + lg*4 + reg;
        unsigned uu = (__float_as_uint(acc[reg]) & 0xffffff00u) | (unsigned)(sidx & 0xff);
        float pv = (sidx < T_) ? __uint_as_float(uu) : -3e38f;
        PINS(pv, v0,v1,v2,v3);
      }
    }
    #pragma unroll
    for (int m=16;m<64;m<<=1){
      float c0=__shfl_xor(v0,m,64), c1=__shfl_xor(v1,m,64),
            c2=__shfl_xor(v2,m,64), c3=__shfl_xor(v3,m,64);
      float d0=fmaxf(v0,c3), d1=fmaxf(v1,c2), d2=fmaxf(v2,c1), d3=fmaxf(v3,c0);
      MM(d0,d1); MM(d2,d3); MM(d0,d2); MM(d1,d3); MM(d1,d2);
      v0=d0; v1=d1; v2=d2; v3=d3;
    }
    if (lg==0){
      unsigned pk = (__float_as_uint(v0) & 0xffu)
                  | ((__float_as_uint(v1) & 0xffu) << 8)
                  | ((__float_as_uint(v2) & 0xffu) << 16)
                  | ((__float_as_uint(v3) & 0xffu) << 24);
      *(unsigned*)(smem + NBROFF + tcol*4) = pk;
    }
  }

  // ---- load + quantize weights to fp8 frags (A-operand: row=out-channel) ----
  long ufr[4], vfr[4];
  {
    const int crw = w*16 + lr;
    #pragma unroll
    for (int kk=0;kk<4;kk++){
      const float4* pu = (const float4*)(Uw + crw*C_ + kk*32 + lg*8);
      float4 a = pu[0], c = pu[1];
      union { long v; unsigned u[2]; } r;
      r.u[0] = pkf8(a.x,a.y,a.z,a.w); r.u[1] = pkf8(c.x,c.y,c.z,c.w);
      ufr[kk] = r.v;
      const float4* pv = (const float4*)(Vw + crw*C_ + kk*32 + lg*8);
      a = pv[0]; c = pv[1];
      r.u[0] = pkf8(a.x,a.y,a.z,a.w); r.u[1] = pkf8(c.x,c.y,c.z,c.w);
      vfr[kk] = r.v;
    }
  }
  const float4 vb4 = *(const float4*)(Vbv + ch0);

  // ---- Pass 1: yv = 0.25*(y@Vw^T + Vb) -> fp8 LDS (16 tiles/wave) ----
  #pragma unroll 4
  for (int tt=0; tt<16; tt++){
    const int t = tt*16 + lr;
    f32x4 accV = {0.f,0.f,0.f,0.f};
    #pragma unroll
    for (int kk=0;kk<4;kk++){
      long yf = *(const long*)(smem + YOFF + t*YSTR + kk*32 + lg*8);
      accV = __builtin_amdgcn_mfma_f32_16x16x32_fp8_fp8(vfr[kk], yf, accV, 0,0,0);
    }
    *(unsigned*)(smem + YVOFF + t*YSTR + ch0) =
        pkf8(0.25f*(accV[0]+vb4.x), 0.25f*(accV[1]+vb4.y),
             0.25f*(accV[2]+vb4.z), 0.25f*(accV[3]+vb4.w));
  }
  __syncthreads();   // barrier 2: nbr + yv ready

  // ---- Pass 2: yU MFMA + gather + BN + ReLU + epilogue, x/att prefetch 1-ahead ----
  const float4 ub4 = *(const float4*)((const float*)(smem+UBOFF) + ch0);
  const float4 ls4 = *(const float4*)((const float*)(smem+LSOFF) + ch0);

  int   t_n  = lr;
  bool  ok_n = true;
  long  g_n  = nbase + (long)t_n*JC + ch0;
  float4 px = *(const float4*)(x+g_n), pa = *(const float4*)(att+g_n);

  #pragma unroll
  for (int tt=0; tt<16; tt++){
    const int   t  = t_n;
    const bool  ok = ok_n;
    const long  g  = g_n;
    const float4 x4 = px, a4 = pa;
    if (tt < 15){
      t_n  = (tt+1)*16 + lr;
      ok_n = t_n < T_;
      g_n  = nbase + (long)t_n*JC + ch0;
      px = make_float4(0,0,0,0); pa = make_float4(0,0,0,0);
      if (ok_n){ px = *(const float4*)(x+g_n); pa = *(const float4*)(att+g_n); }
    }
    f32x4 accU = {0.f,0.f,0.f,0.f};
    #pragma unroll
    for (int kk=0;kk<4;kk++){
      long yf = *(const long*)(smem + YOFF + t*YSTR + kk*32 + lg*8);
      accU = __builtin_amdgcn_mfma_f32_16x16x32_fp8_fp8(ufr[kk], yf, accU, 0,0,0);
    }
    unsigned nb = *(const unsigned*)(smem + NBROFF + t*4);
    const int s0 = (int)(nb & 0xffu), s1 = (int)((nb>>8)&0xffu),
              s2 = (int)((nb>>16)&0xffu), s3 = (int)((nb>>24)&0xffu);
    float ag0=0,ag1=0,ag2=0,ag3=0;
    {
      unsigned q; f32x2 e, o2;
      q = *(const unsigned*)(smem+YVOFF + s0*YSTR + ch0);
      e = __builtin_amdgcn_cvt_pk_f32_fp8(q,false); o2 = __builtin_amdgcn_cvt_pk_f32_fp8(q,true);
      ag0+=e[0]; ag1+=e[1]; ag2+=o2[0]; ag3+=o2[1];
      q = *(const unsigned*)(smem+YVOFF + s1*YSTR + ch0);
      e = __builtin_amdgcn_cvt_pk_f32_fp8(q,false); o2 = __builtin_amdgcn_cvt_pk_f32_fp8(q,true);
      ag0+=e[0]; ag1+=e[1]; ag2+=o2[0]; ag3+=o2[1];
      q = *(const unsigned*)(smem+YVOFF + s2*YSTR + ch0);
      e = __builtin_amdgcn_cvt_pk_f32_fp8(q,false); o2 = __builtin_amdgcn_cvt_pk_f32_fp8(q,true);
      ag0+=e[0]; ag1+=e[1]; ag2+=o2[0]; ag3+=o2[1];
      q = *(const unsigned*)(smem+YVOFF + s3*YSTR + ch0);
      e = __builtin_amdgcn_cvt_pk_f32_fp8(q,false); o2 = __builtin_amdgcn_cvt_pk_f32_fp8(q,true);
      ag0+=e[0]; ag1+=e[1]; ag2+=o2[0]; ag3+=o2[1];
    }
    float yo0,yo1,yo2,yo3;
    {
      unsigned q = *(const unsigned*)(smem + YOFF + t*YSTR + ch0);
      f32x2 e = __builtin_amdgcn_cvt_pk_f32_fp8(q,false);
      f32x2 o2 = __builtin_amdgcn_cvt_pk_f32_fp8(q,true);
      yo0=e[0]; yo1=e[1]; yo2=o2[0]; yo3=o2[1];
    }
    const float bw = ((const float*)(smem+BNWOFF))[t];
    const float bb = ((const float*)(smem+BNBOFF))[t];
    f32x4 o, gf;
    {
      float h = (accU[0] + ag0 + ub4.x)*bw + bb;
      float gx = ls4.x * fmaxf(0.f, yo0 + h);
      o[0] = gx + a4.x + x4.x; gf[0] = gx*0.5f;
    }{
      float h = (accU[1] + ag1 + ub4.y)*bw + bb;
      float gx = ls4.y * fmaxf(0.f, yo1 + h);
      o[1] = gx + a4.y + x4.y; gf[1] = gx*0.5f;
    }{
      float h = (accU[2] + ag2 + ub4.z)*bw + bb;
      float gx = ls4.z * fmaxf(0.f, yo2 + h);
      o[2] = gx + a4.z + x4.z; gf[2] = gx*0.5f;
    }{
      float h = (accU[3] + ag3 + ub4.w)*bw + bb;
      float gx = ls4.w * fmaxf(0.f, yo3 + h);
      o[3] = gx + a4.w + x4.w; gf[3] = gx*0.5f;
    }
    if (ok){
      *(f32x4*)(out+g)      = o;
      *(f32x4*)(out+NTOT+g) = gf;
    }
  }
}

extern "C" void kernel_launch(void* const* d_in, const int* in_sizes, int n_in,
                              void* d_out, int out_size, void* d_ws, size_t ws_size,
                              hipStream_t stream) {
  hipFuncSetAttribute(reinterpret_cast<const void*>(graphblock_kernel),
                      hipFuncAttributeMaxDynamicSharedMemorySize, SMEM_BYTES);
  dim3 grid(B_ * J_);
  dim3 block(512);
  graphblock_kernel<<<grid, block, SMEM_BYTES, stream>>>(
      (const float*)d_in[0],  // x
      (const float*)d_in[1],  // attention_feat
      (const float*)d_in[2],  // ln_w
      (const float*)d_in[3],  // ln_b
      (const float*)d_in[4],  // Uw
      (const float*)d_in[5],  // Ub
      (const float*)d_in[6],  // Vw
      (const float*)d_in[7],  // Vb
      (const float*)d_in[8],  // bn_w
      (const float*)d_in[9],  // bn_b
      (const float*)d_in[10], // ls1
      (float*)d_out);
}

// Round 17
// 185.613 us; speedup vs baseline: 2.0471x; 1.0262x over previous
//
#include <hip/hip_runtime.h>

#define B_ 64
#define T_ 243
#define J_ 17
#define C_ 128
#define JC (J_*C_)            // 2176
#define NTOT (B_*T_*J_*C_)    // 33841152

// LDS layout (bytes). fp8 rows padded to 136 B (bank de-alias).
//   [0,     34816)  ylds : fp8 [256][136]
//   [34816, 69632)  yv   : fp8 [256][136]  (0.25*(y@Vw^T+Vb))
//   [69632, 70656)  nbr  : u32 [256]  (4 x u8 idx)
//   [70656, 71680)  bnw_s: f32 [256] (pre-scaled)
//   [71680, 72704)  bnb_s: f32 [256]
//   [72704, 73216)  ub_s : f32 [128]
//   [73216, 73728)  ls_s : f32 [128]
#define YOFF    0
#define YVOFF   34816
#define NBROFF  69632
#define BNWOFF  70656
#define BNBOFF  71680
#define UBOFF   72704
#define LSOFF   73216
#define SMEM_BYTES 73728
#define YSTR 136

typedef float f32x4 __attribute__((ext_vector_type(4)));
typedef float f32x2 __attribute__((ext_vector_type(2)));

__device__ __forceinline__ unsigned pkf8(float a, float b, float c, float d){
  int p = __builtin_amdgcn_cvt_pk_fp8_f32(a, b, 0, false);
  p = __builtin_amdgcn_cvt_pk_fp8_f32(c, d, p, true);
  return (unsigned)p;
}

template<int CTRL>
__device__ __forceinline__ float dppadd(float v){
  int t = __builtin_amdgcn_update_dpp(0, __float_as_int(v), CTRL, 0xf, 0xf, true);
  return v + __int_as_float(t);
}
__device__ __forceinline__ float swz16(float v){
  return __int_as_float(__builtin_amdgcn_ds_swizzle(__float_as_int(v), 0x401F));
}

#define PINS(x, a0,a1,a2,a3) do { \
  float t_ = fmaxf(a0,(x)), m_ = fminf(a0,(x)); a0 = t_; \
  float t2_ = fmaxf(a1,m_); m_ = fminf(a1,m_); a1 = t2_; \
  float t3_ = fmaxf(a2,m_); m_ = fminf(a2,m_); a2 = t3_; \
  a3 = fmaxf(a3,m_); \
} while(0)
#define MM(p,q) do { float h_=fmaxf(p,q); q=fminf(p,q); p=h_; } while(0)

extern "C" __global__ void __launch_bounds__(512, 4)
graphblock_kernel(const float* __restrict__ x, const float* __restrict__ att,
                  const float* __restrict__ lnw, const float* __restrict__ lnb,
                  const float* __restrict__ Uw, const float* __restrict__ Ubv,
                  const float* __restrict__ Vw, const float* __restrict__ Vbv,
                  const float* __restrict__ bnw, const float* __restrict__ bnb,
                  const float* __restrict__ ls1, float* __restrict__ out)
{
  extern __shared__ char smem[];
  const int tid = threadIdx.x;
  const int w = tid >> 6, l = tid & 63;    // 8 waves
  const int lr = l & 15, lg = l >> 4;
  const int n = blockIdx.x, b = n / J_, j = n % J_;
  const long nbase = (long)b*T_*JC + (long)j*C_;
  const int ch0 = w*16 + lg*4;             // lane's 4-channel base (UV passes)

  // ---- table staging ----
  if (tid < 256) {
    bool v = tid < T_;
    ((float*)(smem+BNWOFF))[tid] = v ? bnw[tid]*rsqrtf(1.0f+1e-5f) : 0.f;
    ((float*)(smem+BNBOFF))[tid] = v ? bnb[tid] : 0.f;
  } else if (tid < 384) {
    int c = tid - 256;
    ((float*)(smem+UBOFF))[c] = Ubv[c];
    ((float*)(smem+LSOFF))[c] = ls1[c];
  }

  // ---- Phase A: LayerNorm -> ylds fp8 ; 2 batches of 8-deep prefetch ----
  {
    const int lh = l >> 5, lc = l & 31;
    const float4 lw4 = *(const float4*)(lnw + lc*4);
    const float4 lb4 = *(const float4*)(lnb + lc*4);
    #pragma unroll
    for (int g2=0; g2<2; g2++){
      float4 p[8];
      #pragma unroll
      for (int i=0;i<8;i++){
        const int r = (g2*8+i)*16 + w*2 + lh;
        p[i] = make_float4(0.f,0.f,0.f,0.f);
        if (r < T_) p[i] = *(const float4*)(x + nbase + (long)r*JC + lc*4);
      }
      #pragma unroll
      for (int i=0;i<8;i++){
        const int r = (g2*8+i)*16 + w*2 + lh;
        unsigned pk = 0u;
        if (r < T_) {
          float4 v = p[i];
          float s = (v.x+v.y)+(v.z+v.w);
          float q = (v.x*v.x+v.y*v.y)+(v.z*v.z+v.w*v.w);
          s = dppadd<0xB1>(s);  q = dppadd<0xB1>(q);
          s = dppadd<0x4E>(s);  q = dppadd<0x4E>(q);
          s = dppadd<0x124>(s); q = dppadd<0x124>(q);
          s = dppadd<0x128>(s); q = dppadd<0x128>(q);
          s += swz16(s);        q += swz16(q);
          float mu = s*(1.f/128.f);
          float rs = rsqrtf(q*(1.f/128.f)-mu*mu+1e-5f);
          pk = pkf8((v.x-mu)*rs*lw4.x+lb4.x, (v.y-mu)*rs*lw4.y+lb4.y,
                    (v.z-mu)*rs*lw4.z+lb4.z, (v.w-mu)*rs*lw4.w+lb4.w);
        }
        *(unsigned*)(smem + YOFF + r*YSTR + lc*4) = pk;
      }
    }
  }
  __syncthreads();   // barrier 1: ylds + tables ready

  // ---- Phase C: sim (fp8 MFMA, swapped operands) + per-lane top-4; 2 halves ----
  #pragma unroll
  for (int half=0; half<2; half++){
    const int tcol = half*128 + w*16 + lr;   // this lane's t (D column)
    long bfr[4];
    #pragma unroll
    for (int kk=0;kk<4;kk++)
      bfr[kk] = *(const long*)(smem + YOFF + tcol*YSTR + kk*32 + lg*8);
    float v0=-3e38f, v1=-3e38f, v2=-3e38f, v3=-3e38f;
    #pragma unroll 4
    for (int st=0; st<16; st++){
      f32x4 acc = {0.f,0.f,0.f,0.f};
      #pragma unroll
      for (int kk=0;kk<4;kk++){
        long afr = *(const long*)(smem + YOFF + (st*16+lr)*YSTR + kk*32 + lg*8);
        acc = __builtin_amdgcn_mfma_f32_16x16x32_fp8_fp8(afr, bfr[kk], acc, 0,0,0);
      }
      #pragma unroll
      for (int reg=0;reg<4;reg++){
        const int sidx = st*16 + lg*4 + reg;
        unsigned uu = (__float_as_uint(acc[reg]) & 0xffffff00u) | (unsigned)(sidx & 0xff);
        float pv = (sidx < T_) ? __uint_as_float(uu) : -3e38f;
        PINS(pv, v0,v1,v2,v3);
      }
    }
    #pragma unroll
    for (int m=16;m<64;m<<=1){
      float c0=__shfl_xor(v0,m,64), c1=__shfl_xor(v1,m,64),
            c2=__shfl_xor(v2,m,64), c3=__shfl_xor(v3,m,64);
      float d0=fmaxf(v0,c3), d1=fmaxf(v1,c2), d2=fmaxf(v2,c1), d3=fmaxf(v3,c0);
      MM(d0,d1); MM(d2,d3); MM(d0,d2); MM(d1,d3); MM(d1,d2);
      v0=d0; v1=d1; v2=d2; v3=d3;
    }
    if (lg==0){
      unsigned pk = (__float_as_uint(v0) & 0xffu)
                  | ((__float_as_uint(v1) & 0xffu) << 8)
                  | ((__float_as_uint(v2) & 0xffu) << 16)
                  | ((__float_as_uint(v3) & 0xffu) << 24);
      *(unsigned*)(smem + NBROFF + tcol*4) = pk;
    }
  }

  // ---- load + quantize weights to fp8 frags (A-operand: row=out-channel) ----
  long ufr[4], vfr[4];
  {
    const int crw = w*16 + lr;
    #pragma unroll
    for (int kk=0;kk<4;kk++){
      const float4* pu = (const float4*)(Uw + crw*C_ + kk*32 + lg*8);
      float4 a = pu[0], c = pu[1];
      union { long v; unsigned u[2]; } r;
      r.u[0] = pkf8(a.x,a.y,a.z,a.w); r.u[1] = pkf8(c.x,c.y,c.z,c.w);
      ufr[kk] = r.v;
      const float4* pv = (const float4*)(Vw + crw*C_ + kk*32 + lg*8);
      a = pv[0]; c = pv[1];
      r.u[0] = pkf8(a.x,a.y,a.z,a.w); r.u[1] = pkf8(c.x,c.y,c.z,c.w);
      vfr[kk] = r.v;
    }
  }
  const float4 vb4 = *(const float4*)(Vbv + ch0);

  // ---- prologue: issue tiles 0,1 x/att prefetch (hidden under pass 1 MFMAs) ----
  int    tA[2];  bool okA[2];  long gA[2];
  float4 pxA[2], paA[2];
  #pragma unroll
  for (int i=0;i<2;i++){
    const int t = i*16 + lr;            // tiles 0,1: always < 243
    tA[i] = t; okA[i] = true;
    gA[i] = nbase + (long)t*JC + ch0;
    pxA[i] = *(const float4*)(x+gA[i]);
    paA[i] = *(const float4*)(att+gA[i]);
  }

  // ---- Pass 1: yv = 0.25*(y@Vw^T + Vb) -> fp8 LDS (16 tiles/wave) ----
  #pragma unroll 4
  for (int tt=0; tt<16; tt++){
    const int t = tt*16 + lr;
    f32x4 accV = {0.f,0.f,0.f,0.f};
    #pragma unroll
    for (int kk=0;kk<4;kk++){
      long yf = *(const long*)(smem + YOFF + t*YSTR + kk*32 + lg*8);
      accV = __builtin_amdgcn_mfma_f32_16x16x32_fp8_fp8(vfr[kk], yf, accV, 0,0,0);
    }
    *(unsigned*)(smem + YVOFF + t*YSTR + ch0) =
        pkf8(0.25f*(accV[0]+vb4.x), 0.25f*(accV[1]+vb4.y),
             0.25f*(accV[2]+vb4.z), 0.25f*(accV[3]+vb4.w));
  }
  __syncthreads();   // barrier 2: nbr + yv ready

  // ---- Pass 2: yU MFMA + gather + BN + ReLU + epilogue, 2-deep x/att prefetch ----
  const float4 ub4 = *(const float4*)((const float*)(smem+UBOFF) + ch0);
  const float4 ls4 = *(const float4*)((const float*)(smem+LSOFF) + ch0);

  #pragma unroll
  for (int tt=0; tt<16; tt++){
    const int slot = tt & 1;
    const int   t  = tA[slot];
    const bool  ok = okA[slot];
    const long  g  = gA[slot];
    const float4 x4 = pxA[slot], a4 = paA[slot];
    if (tt < 14){
      const int tn = (tt+2)*16 + lr;
      tA[slot]  = tn;
      okA[slot] = tn < T_;
      gA[slot]  = nbase + (long)tn*JC + ch0;
      pxA[slot] = make_float4(0,0,0,0); paA[slot] = make_float4(0,0,0,0);
      if (okA[slot]){ pxA[slot] = *(const float4*)(x+gA[slot]); paA[slot] = *(const float4*)(att+gA[slot]); }
    }
    // hoist LDS scalar/table reads so their latency overlaps the MFMAs below
    const unsigned nb = *(const unsigned*)(smem + NBROFF + t*4);
    const float bw = ((const float*)(smem+BNWOFF))[t];
    const float bb = ((const float*)(smem+BNBOFF))[t];
    const unsigned yq = *(const unsigned*)(smem + YOFF + t*YSTR + ch0);
    f32x4 accU = {0.f,0.f,0.f,0.f};
    #pragma unroll
    for (int kk=0;kk<4;kk++){
      long yf = *(const long*)(smem + YOFF + t*YSTR + kk*32 + lg*8);
      accU = __builtin_amdgcn_mfma_f32_16x16x32_fp8_fp8(ufr[kk], yf, accU, 0,0,0);
    }
    const int s0 = (int)(nb & 0xffu), s1 = (int)((nb>>8)&0xffu),
              s2 = (int)((nb>>16)&0xffu), s3 = (int)((nb>>24)&0xffu);
    float ag0=0,ag1=0,ag2=0,ag3=0;
    {
      unsigned q; f32x2 e, o2;
      q = *(const unsigned*)(smem+YVOFF + s0*YSTR + ch0);
      e = __builtin_amdgcn_cvt_pk_f32_fp8(q,false); o2 = __builtin_amdgcn_cvt_pk_f32_fp8(q,true);
      ag0+=e[0]; ag1+=e[1]; ag2+=o2[0]; ag3+=o2[1];
      q = *(const unsigned*)(smem+YVOFF + s1*YSTR + ch0);
      e = __builtin_amdgcn_cvt_pk_f32_fp8(q,false); o2 = __builtin_amdgcn_cvt_pk_f32_fp8(q,true);
      ag0+=e[0]; ag1+=e[1]; ag2+=o2[0]; ag3+=o2[1];
      q = *(const unsigned*)(smem+YVOFF + s2*YSTR + ch0);
      e = __builtin_amdgcn_cvt_pk_f32_fp8(q,false); o2 = __builtin_amdgcn_cvt_pk_f32_fp8(q,true);
      ag0+=e[0]; ag1+=e[1]; ag2+=o2[0]; ag3+=o2[1];
      q = *(const unsigned*)(smem+YVOFF + s3*YSTR + ch0);
      e = __builtin_amdgcn_cvt_pk_f32_fp8(q,false); o2 = __builtin_amdgcn_cvt_pk_f32_fp8(q,true);
      ag0+=e[0]; ag1+=e[1]; ag2+=o2[0]; ag3+=o2[1];
    }
    float yo0,yo1,yo2,yo3;
    {
      f32x2 e = __builtin_amdgcn_cvt_pk_f32_fp8(yq,false);
      f32x2 o2 = __builtin_amdgcn_cvt_pk_f32_fp8(yq,true);
      yo0=e[0]; yo1=e[1]; yo2=o2[0]; yo3=o2[1];
    }
    f32x4 o, gf;
    {
      float h = (accU[0] + ag0 + ub4.x)*bw + bb;
      float gx = ls4.x * fmaxf(0.f, yo0 + h);
      o[0] = gx + a4.x + x4.x; gf[0] = gx*0.5f;
    }{
      float h = (accU[1] + ag1 + ub4.y)*bw + bb;
      float gx = ls4.y * fmaxf(0.f, yo1 + h);
      o[1] = gx + a4.y + x4.y; gf[1] = gx*0.5f;
    }{
      float h = (accU[2] + ag2 + ub4.z)*bw + bb;
      float gx = ls4.z * fmaxf(0.f, yo2 + h);
      o[2] = gx + a4.z + x4.z; gf[2] = gx*0.5f;
    }{
      float h = (accU[3] + ag3 + ub4.w)*bw + bb;
      float gx = ls4.w * fmaxf(0.f, yo3 + h);
      o[3] = gx + a4.w + x4.w; gf[3] = gx*0.5f;
    }
    if (ok){
      *(f32x4*)(out+g)      = o;
      *(f32x4*)(out+NTOT+g) = gf;
    }
  }
}

extern "C" void kernel_launch(void* const* d_in, const int* in_sizes, int n_in,
                              void* d_out, int out_size, void* d_ws, size_t ws_size,
                              hipStream_t stream) {
  hipFuncSetAttribute(reinterpret_cast<const void*>(graphblock_kernel),
                      hipFuncAttributeMaxDynamicSharedMemorySize, SMEM_BYTES);
  dim3 grid(B_ * J_);
  dim3 block(512);
  graphblock_kernel<<<grid, block, SMEM_BYTES, stream>>>(
      (const float*)d_in[0],  // x
      (const float*)d_in[1],  // attention_feat
      (const float*)d_in[2],  // ln_w
      (const float*)d_in[3],  // ln_b
      (const float*)d_in[4],  // Uw
      (const float*)d_in[5],  // Ub
      (const float*)d_in[6],  // Vw
      (const float*)d_in[7],  // Vb
      (const float*)d_in[8],  // bn_w
      (const float*)d_in[9],  // bn_b
      (const float*)d_in[10], // ls1
      (float*)d_out);
}

// Round 18
// 184.927 us; speedup vs baseline: 2.0547x; 1.0037x over previous
//
#include <hip/hip_runtime.h>

#define B_ 64
#define T_ 243
#define J_ 17
#define C_ 128
#define JC (J_*C_)            // 2176
#define NTOT (B_*T_*J_*C_)    // 33841152

// LDS layout (bytes). fp8 rows padded to 136 B (bank de-alias).
//   [0,     34816)  ylds : fp8 [256][136]
//   [34816, 69632)  yv   : fp8 [256][136]  (0.25*(y@Vw^T+Vb))
//   [69632, 70656)  nbr  : u32 [256]  (4 x u8 idx)
//   [70656, 71680)  bnw_s: f32 [256] (pre-scaled)
//   [71680, 72704)  bnb_s: f32 [256]
//   [72704, 73216)  ub_s : f32 [128]
//   [73216, 73728)  ls_s : f32 [128]
#define YOFF    0
#define YVOFF   34816
#define NBROFF  69632
#define BNWOFF  70656
#define BNBOFF  71680
#define UBOFF   72704
#define LSOFF   73216
#define SMEM_BYTES 73728
#define YSTR 136

typedef float f32x4 __attribute__((ext_vector_type(4)));
typedef float f32x2 __attribute__((ext_vector_type(2)));

__device__ __forceinline__ unsigned pkf8(float a, float b, float c, float d){
  int p = __builtin_amdgcn_cvt_pk_fp8_f32(a, b, 0, false);
  p = __builtin_amdgcn_cvt_pk_fp8_f32(c, d, p, true);
  return (unsigned)p;
}

template<int CTRL>
__device__ __forceinline__ float dppadd(float v){
  int t = __builtin_amdgcn_update_dpp(0, __float_as_int(v), CTRL, 0xf, 0xf, true);
  return v + __int_as_float(t);
}
__device__ __forceinline__ float swz16(float v){
  return __int_as_float(__builtin_amdgcn_ds_swizzle(__float_as_int(v), 0x401F));
}

#define PINS(x, a0,a1,a2,a3) do { \
  float t_ = fmaxf(a0,(x)), m_ = fminf(a0,(x)); a0 = t_; \
  float t2_ = fmaxf(a1,m_); m_ = fminf(a1,m_); a1 = t2_; \
  float t3_ = fmaxf(a2,m_); m_ = fminf(a2,m_); a2 = t3_; \
  a3 = fmaxf(a3,m_); \
} while(0)
#define MM(p,q) do { float h_=fmaxf(p,q); q=fminf(p,q); p=h_; } while(0)

extern "C" __global__ void __launch_bounds__(512, 4)
graphblock_kernel(const float* __restrict__ x, const float* __restrict__ att,
                  const float* __restrict__ lnw, const float* __restrict__ lnb,
                  const float* __restrict__ Uw, const float* __restrict__ Ubv,
                  const float* __restrict__ Vw, const float* __restrict__ Vbv,
                  const float* __restrict__ bnw, const float* __restrict__ bnb,
                  const float* __restrict__ ls1, float* __restrict__ out)
{
  extern __shared__ char smem[];
  const int tid = threadIdx.x;
  const int w = tid >> 6, l = tid & 63;    // 8 waves
  const int lr = l & 15, lg = l >> 4;
  const int n = blockIdx.x, b = n / J_, j = n % J_;
  const long nbase = (long)b*T_*JC + (long)j*C_;
  const int ch0 = w*16 + lg*4;             // lane's 4-channel base (UV passes)

  // ---- table staging ----
  if (tid < 256) {
    bool v = tid < T_;
    ((float*)(smem+BNWOFF))[tid] = v ? bnw[tid]*rsqrtf(1.0f+1e-5f) : 0.f;
    ((float*)(smem+BNBOFF))[tid] = v ? bnb[tid] : 0.f;
  } else if (tid < 384) {
    int c = tid - 256;
    ((float*)(smem+UBOFF))[c] = Ubv[c];
    ((float*)(smem+LSOFF))[c] = ls1[c];
  }

  // ---- Phase A: LayerNorm -> ylds fp8 ; 2 batches of 8-deep prefetch ----
  {
    const int lh = l >> 5, lc = l & 31;
    const float4 lw4 = *(const float4*)(lnw + lc*4);
    const float4 lb4 = *(const float4*)(lnb + lc*4);
    #pragma unroll
    for (int g2=0; g2<2; g2++){
      float4 p[8];
      #pragma unroll
      for (int i=0;i<8;i++){
        const int r = (g2*8+i)*16 + w*2 + lh;
        p[i] = make_float4(0.f,0.f,0.f,0.f);
        if (r < T_) p[i] = *(const float4*)(x + nbase + (long)r*JC + lc*4);
      }
      #pragma unroll
      for (int i=0;i<8;i++){
        const int r = (g2*8+i)*16 + w*2 + lh;
        unsigned pk = 0u;
        if (r < T_) {
          float4 v = p[i];
          float s = (v.x+v.y)+(v.z+v.w);
          float q = (v.x*v.x+v.y*v.y)+(v.z*v.z+v.w*v.w);
          s = dppadd<0xB1>(s);  q = dppadd<0xB1>(q);
          s = dppadd<0x4E>(s);  q = dppadd<0x4E>(q);
          s = dppadd<0x124>(s); q = dppadd<0x124>(q);
          s = dppadd<0x128>(s); q = dppadd<0x128>(q);
          s += swz16(s);        q += swz16(q);
          float mu = s*(1.f/128.f);
          float rs = rsqrtf(q*(1.f/128.f)-mu*mu+1e-5f);
          pk = pkf8((v.x-mu)*rs*lw4.x+lb4.x, (v.y-mu)*rs*lw4.y+lb4.y,
                    (v.z-mu)*rs*lw4.z+lb4.z, (v.w-mu)*rs*lw4.w+lb4.w);
        }
        *(unsigned*)(smem + YOFF + r*YSTR + lc*4) = pk;
      }
    }
  }
  __syncthreads();   // barrier 1: ylds + tables ready

  // ---- Phase C: sim (fp8 MFMA, swapped operands) + per-lane top-4; 2 halves ----
  #pragma unroll
  for (int half=0; half<2; half++){
    const int tcol = half*128 + w*16 + lr;   // this lane's t (D column)
    long bfr[4];
    #pragma unroll
    for (int kk=0;kk<4;kk++)
      bfr[kk] = *(const long*)(smem + YOFF + tcol*YSTR + kk*32 + lg*8);
    float v0=-3e38f, v1=-3e38f, v2=-3e38f, v3=-3e38f;
    #pragma unroll 4
    for (int st=0; st<16; st++){
      f32x4 acc = {0.f,0.f,0.f,0.f};
      #pragma unroll
      for (int kk=0;kk<4;kk++){
        long afr = *(const long*)(smem + YOFF + (st*16+lr)*YSTR + kk*32 + lg*8);
        acc = __builtin_amdgcn_mfma_f32_16x16x32_fp8_fp8(afr, bfr[kk], acc, 0,0,0);
      }
      #pragma unroll
      for (int reg=0;reg<4;reg++){
        const int sidx = st*16 + lg*4 + reg;
        unsigned uu = (__float_as_uint(acc[reg]) & 0xffffff00u) | (unsigned)(sidx & 0xff);
        float pv = (sidx < T_) ? __uint_as_float(uu) : -3e38f;
        PINS(pv, v0,v1,v2,v3);
      }
    }
    #pragma unroll
    for (int m=16;m<64;m<<=1){
      float c0=__shfl_xor(v0,m,64), c1=__shfl_xor(v1,m,64),
            c2=__shfl_xor(v2,m,64), c3=__shfl_xor(v3,m,64);
      float d0=fmaxf(v0,c3), d1=fmaxf(v1,c2), d2=fmaxf(v2,c1), d3=fmaxf(v3,c0);
      MM(d0,d1); MM(d2,d3); MM(d0,d2); MM(d1,d3); MM(d1,d2);
      v0=d0; v1=d1; v2=d2; v3=d3;
    }
    if (lg==0){
      unsigned pk = (__float_as_uint(v0) & 0xffu)
                  | ((__float_as_uint(v1) & 0xffu) << 8)
                  | ((__float_as_uint(v2) & 0xffu) << 16)
                  | ((__float_as_uint(v3) & 0xffu) << 24);
      *(unsigned*)(smem + NBROFF + tcol*4) = pk;
    }
  }

  // ---- load + quantize weights to fp8 frags (A-operand: row=out-channel) ----
  long ufr[4], vfr[4];
  {
    const int crw = w*16 + lr;
    #pragma unroll
    for (int kk=0;kk<4;kk++){
      const float4* pu = (const float4*)(Uw + crw*C_ + kk*32 + lg*8);
      float4 a = pu[0], c = pu[1];
      union { long v; unsigned u[2]; } r;
      r.u[0] = pkf8(a.x,a.y,a.z,a.w); r.u[1] = pkf8(c.x,c.y,c.z,c.w);
      ufr[kk] = r.v;
      const float4* pv = (const float4*)(Vw + crw*C_ + kk*32 + lg*8);
      a = pv[0]; c = pv[1];
      r.u[0] = pkf8(a.x,a.y,a.z,a.w); r.u[1] = pkf8(c.x,c.y,c.z,c.w);
      vfr[kk] = r.v;
    }
  }
  const float4 vb4 = *(const float4*)(Vbv + ch0);

  // ---- prologue: issue tiles 0,1,2 x/att prefetch (hidden under pass 1 MFMAs) ----
  int    tA[3];  bool okA[3];  long gA[3];
  float4 pxA[3], paA[3];
  #pragma unroll
  for (int i=0;i<3;i++){
    const int t = i*16 + lr;            // tiles 0..2: always < 243
    tA[i] = t; okA[i] = true;
    gA[i] = nbase + (long)t*JC + ch0;
    pxA[i] = *(const float4*)(x+gA[i]);
    paA[i] = *(const float4*)(att+gA[i]);
  }

  // ---- Pass 1 (merged UV): one A-frag read -> accU (fp8 regs) + yv (LDS) ----
  unsigned hu[16];
  #pragma unroll
  for (int tt=0; tt<16; tt++){
    const int t = tt*16 + lr;
    f32x4 accV = {0.f,0.f,0.f,0.f}, accU = {0.f,0.f,0.f,0.f};
    #pragma unroll
    for (int kk=0;kk<4;kk++){
      long yf = *(const long*)(smem + YOFF + t*YSTR + kk*32 + lg*8);
      accU = __builtin_amdgcn_mfma_f32_16x16x32_fp8_fp8(ufr[kk], yf, accU, 0,0,0);
      accV = __builtin_amdgcn_mfma_f32_16x16x32_fp8_fp8(vfr[kk], yf, accV, 0,0,0);
    }
    *(unsigned*)(smem + YVOFF + t*YSTR + ch0) =
        pkf8(0.25f*(accV[0]+vb4.x), 0.25f*(accV[1]+vb4.y),
             0.25f*(accV[2]+vb4.z), 0.25f*(accV[3]+vb4.w));
    hu[tt] = pkf8(accU[0], accU[1], accU[2], accU[3]);
  }
  __syncthreads();   // barrier 2: nbr + yv ready

  // ---- Pass 2 (MFMA-free stream): gather + BN + ReLU + epilogue, 3-deep prefetch ----
  const float4 ub4 = *(const float4*)((const float*)(smem+UBOFF) + ch0);
  const float4 ls4 = *(const float4*)((const float*)(smem+LSOFF) + ch0);

  #pragma unroll
  for (int tt=0; tt<16; tt++){
    const int slot = tt % 3;
    const int   t  = tA[slot];
    const bool  ok = okA[slot];
    const long  g  = gA[slot];
    const float4 x4 = pxA[slot], a4 = paA[slot];
    if (tt < 13){
      const int tn = (tt+3)*16 + lr;
      tA[slot]  = tn;
      okA[slot] = tn < T_;
      gA[slot]  = nbase + (long)tn*JC + ch0;
      pxA[slot] = make_float4(0,0,0,0); paA[slot] = make_float4(0,0,0,0);
      if (okA[slot]){ pxA[slot] = *(const float4*)(x+gA[slot]); paA[slot] = *(const float4*)(att+gA[slot]); }
    }
    // hoisted LDS reads (latency overlaps the gather below)
    const unsigned nb = *(const unsigned*)(smem + NBROFF + t*4);
    const float bw = ((const float*)(smem+BNWOFF))[t];
    const float bb = ((const float*)(smem+BNBOFF))[t];
    const unsigned yq = *(const unsigned*)(smem + YOFF + t*YSTR + ch0);
    const int s0 = (int)(nb & 0xffu), s1 = (int)((nb>>8)&0xffu),
              s2 = (int)((nb>>16)&0xffu), s3 = (int)((nb>>24)&0xffu);
    float ag0=0,ag1=0,ag2=0,ag3=0;
    {
      unsigned q; f32x2 e, o2;
      q = *(const unsigned*)(smem+YVOFF + s0*YSTR + ch0);
      e = __builtin_amdgcn_cvt_pk_f32_fp8(q,false); o2 = __builtin_amdgcn_cvt_pk_f32_fp8(q,true);
      ag0+=e[0]; ag1+=e[1]; ag2+=o2[0]; ag3+=o2[1];
      q = *(const unsigned*)(smem+YVOFF + s1*YSTR + ch0);
      e = __builtin_amdgcn_cvt_pk_f32_fp8(q,false); o2 = __builtin_amdgcn_cvt_pk_f32_fp8(q,true);
      ag0+=e[0]; ag1+=e[1]; ag2+=o2[0]; ag3+=o2[1];
      q = *(const unsigned*)(smem+YVOFF + s2*YSTR + ch0);
      e = __builtin_amdgcn_cvt_pk_f32_fp8(q,false); o2 = __builtin_amdgcn_cvt_pk_f32_fp8(q,true);
      ag0+=e[0]; ag1+=e[1]; ag2+=o2[0]; ag3+=o2[1];
      q = *(const unsigned*)(smem+YVOFF + s3*YSTR + ch0);
      e = __builtin_amdgcn_cvt_pk_f32_fp8(q,false); o2 = __builtin_amdgcn_cvt_pk_f32_fp8(q,true);
      ag0+=e[0]; ag1+=e[1]; ag2+=o2[0]; ag3+=o2[1];
    }
    float u0,u1,u2,u3, yo0,yo1,yo2,yo3;
    {
      f32x2 e = __builtin_amdgcn_cvt_pk_f32_fp8(hu[tt],false);
      f32x2 o2 = __builtin_amdgcn_cvt_pk_f32_fp8(hu[tt],true);
      u0=e[0]; u1=e[1]; u2=o2[0]; u3=o2[1];
      e = __builtin_amdgcn_cvt_pk_f32_fp8(yq,false);
      o2 = __builtin_amdgcn_cvt_pk_f32_fp8(yq,true);
      yo0=e[0]; yo1=e[1]; yo2=o2[0]; yo3=o2[1];
    }
    f32x4 o, gf;
    {
      float h = (u0 + ag0 + ub4.x)*bw + bb;
      float gx = ls4.x * fmaxf(0.f, yo0 + h);
      o[0] = gx + a4.x + x4.x; gf[0] = gx*0.5f;
    }{
      float h = (u1 + ag1 + ub4.y)*bw + bb;
      float gx = ls4.y * fmaxf(0.f, yo1 + h);
      o[1] = gx + a4.y + x4.y; gf[1] = gx*0.5f;
    }{
      float h = (u2 + ag2 + ub4.z)*bw + bb;
      float gx = ls4.z * fmaxf(0.f, yo2 + h);
      o[2] = gx + a4.z + x4.z; gf[2] = gx*0.5f;
    }{
      float h = (u3 + ag3 + ub4.w)*bw + bb;
      float gx = ls4.w * fmaxf(0.f, yo3 + h);
      o[3] = gx + a4.w + x4.w; gf[3] = gx*0.5f;
    }
    if (ok){
      *(f32x4*)(out+g)      = o;
      *(f32x4*)(out+NTOT+g) = gf;
    }
  }
}

extern "C" void kernel_launch(void* const* d_in, const int* in_sizes, int n_in,
                              void* d_out, int out_size, void* d_ws, size_t ws_size,
                              hipStream_t stream) {
  hipFuncSetAttribute(reinterpret_cast<const void*>(graphblock_kernel),
                      hipFuncAttributeMaxDynamicSharedMemorySize, SMEM_BYTES);
  dim3 grid(B_ * J_);
  dim3 block(512);
  graphblock_kernel<<<grid, block, SMEM_BYTES, stream>>>(
      (const float*)d_in[0],  // x
      (const float*)d_in[1],  // attention_feat
      (const float*)d_in[2],  // ln_w
      (const float*)d_in[3],  // ln_b
      (const float*)d_in[4],  // Uw
      (const float*)d_in[5],  // Ub
      (const float*)d_in[6],  // Vw
      (const float*)d_in[7],  // Vb
      (const float*)d_in[8],  // bn_w
      (const float*)d_in[9],  // bn_b
      (const float*)d_in[10], // ls1
      (float*)d_out);
}